// Round 10
// baseline (384.857 us; speedup 1.0000x reference)
//
#include <hip/hip_runtime.h>
#include <hip/hip_bf16.h>

// ---------------------------------------------------------------------------
//   x_e  [2,128,24,24,24]   pred [2,32,96,96,96]   out [2,3,96,96,96] fp32
//   conv(128->256,k3,s2,VALID) -> 11^3 positions; mean∘conv commutes =>
//   conv+pool collapses to 27 separable window-sums per channel (exact).
//   2 launches:
//   K_A (256 blocks): per-channel stats -> 8-block group micro-spin ->
//                     GN+ReLU staged in LDS -> separable winsum. + prefetch.
//   K_B (1728 blocks): xfeat(128 blk) -> flag chain ctrl1(24)->ctrl2(12)->
//                     ctrl3(blk 0) -> effw; ALL blocks preload 32 pred float4
//                     into regs first, spin on final flag, combine, store.
//   Sync: agent-scope ACQ_REL fetch_add arrivals + ACQUIRE load polls
//   (R8-validated cross-XCD pattern).  Flags memset to 0 each replay.
// ---------------------------------------------------------------------------

#define P4 221184        // 96^3/4

typedef float v4f __attribute__((ext_vector_type(4)));

// ws float offsets
#define WS_STATSPART 0       // 256 x float2 = 512 floats  [b*128+c]
#define WS_WINS      512     // [2][128][27] = 6912
#define WS_XF        7424    // 512
#define WS_P         7936    // 6*512 = 3072
#define WS_C         11008   // 6*256 = 1536
#define WS_EFFW      12544   // 192
#define WS_SYNC      12800   // 36 ints: [0..31] grp counters, [32..35] f0..f3
#define WS_SINK      12864

#define AGENT __HIP_MEMORY_SCOPE_AGENT

__device__ __forceinline__ void arrive(int* f) {
  __hip_atomic_fetch_add(f, 1, __ATOMIC_ACQ_REL, AGENT);
}
__device__ __forceinline__ void wait_cnt(int* f, int n) {
  if (threadIdx.x == 0) {
    while (__hip_atomic_load(f, __ATOMIC_ACQUIRE, AGENT) < n)
      __builtin_amdgcn_s_sleep(4);
  }
  __syncthreads();
}

// ---------------------------------------------------------------------------
// K_A: 256 blocks, one per (b,c) channel slice (13824 floats).
// ---------------------------------------------------------------------------
__global__ __launch_bounds__(256) void kA_winsum(
    const float* __restrict__ x_e, const float* __restrict__ gn_g,
    const float* __restrict__ gn_b, const float* __restrict__ gap_w,
    const float* __restrict__ w_cf, const float* __restrict__ w_c,
    const float* __restrict__ w_a1, const float* __restrict__ emb,
    float* __restrict__ ws) {
  __shared__ float stage[13824];   // [zz][yy][xx]
  __shared__ float sx[1728];       // [zz*24+yy][3]
  __shared__ float sxy[216];       // [zz][ky*3+kx]
  __shared__ float red[8];
  int* sync = (int*)(ws + WS_SYNC);
  const int blk = blockIdx.x;      // b*128 + c
  const int t = threadIdx.x;
  const int c = blk & 127;

  // ---- per-channel stats partial ----
  const float4* p = (const float4*)(x_e + (size_t)blk * 13824);
  {
    float s = 0.f, ss = 0.f;
    for (int i = t; i < 3456; i += 256) {
      float4 v = p[i];
      s  += v.x + v.y + v.z + v.w;
      ss += v.x*v.x + v.y*v.y + v.z*v.z + v.w*v.w;
    }
    #pragma unroll
    for (int off = 32; off; off >>= 1) {
      s  += __shfl_down(s, off);
      ss += __shfl_down(ss, off);
    }
    if ((t & 63) == 0) { red[(t >> 6) * 2] = s; red[(t >> 6) * 2 + 1] = ss; }
    __syncthreads();
    if (t == 0) {
      float2 r;
      r.x = red[0] + red[2] + red[4] + red[6];
      r.y = red[1] + red[3] + red[5] + red[7];
      ((float2*)(ws + WS_STATSPART))[blk] = r;
      arrive(&sync[blk >> 3]);               // release: partial visible
    }
  }

  // ---- L3 weight prefetch (overlaps group spin) ----
  {
    float sink = 0.f;
    int tid = blk * 256 + t;                 // 0..65535
    const float4* g4 = (const float4*)gap_w; // 221184 f4
    for (int i = tid; i < 221184; i += 65536) { float4 v = g4[i]; sink += v.x + v.w; }
    if (tid < 65536) { float4 v = ((const float4*)w_cf)[tid]; sink += v.x + v.w; }
    if (tid < 32768) { float4 v = ((const float4*)w_c)[tid];  sink += v.x + v.w; }
    if (tid < 1024)  { float4 v = ((const float4*)w_a1)[tid]; sink += v.x; }
    if (tid < 192)   { float4 v = ((const float4*)emb)[tid];  sink += v.x; }
    if (sink == 1.2345e30f) ws[WS_SINK] = sink;   // never taken
  }

  // ---- group micro-spin: 8 channel-blocks per GN group ----
  wait_cnt(&sync[blk >> 3], 8);

  // ---- finalize stats, GN+ReLU stage, separable winsum ----
  const float2* sp = ((const float2*)(ws + WS_STATSPART)) + (blk & ~7);
  float S = 0.f, SS = 0.f;
  #pragma unroll
  for (int j = 0; j < 8; j++) { float2 r = sp[j]; S += r.x; SS += r.y; }
  float mu   = S * (1.f / 110592.f);
  float var  = SS * (1.f / 110592.f) - mu * mu;
  float rstd = rsqrtf(var + 1e-5f);
  float ga = gn_g[c] * rstd;
  float be = gn_b[c] - mu * ga;

  float4* l4 = (float4*)stage;
  for (int i = t; i < 3456; i += 256) {
    float4 v = p[i];
    float4 r;
    r.x = fmaxf(v.x * ga + be, 0.f);
    r.y = fmaxf(v.y * ga + be, 0.f);
    r.z = fmaxf(v.z * ga + be, 0.f);
    r.w = fmaxf(v.w * ga + be, 0.f);
    l4[i] = r;
  }
  __syncthreads();

  // pass A: 576 rows -> 3 x-sums each
  for (int r = t; r < 576; r += 256) {
    const float* v = stage + r * 24;
    float e1 = 0.f, o = 0.f, e2 = 0.f;
    #pragma unroll
    for (int xx = 0; xx < 11; xx++) {
      e1 += v[2 * xx];
      o  += v[2 * xx + 1];
      e2 += v[2 * xx + 2];
    }
    sx[r * 3 + 0] = e1;
    sx[r * 3 + 1] = o;
    sx[r * 3 + 2] = e2;
  }
  __syncthreads();
  // pass B: 72 tasks (zz,kx) -> 3 y-sums
  if (t < 72) {
    int zz = t / 3, kx = t % 3;
    const float* v = sx + zz * 72 + kx;
    float e1 = 0.f, o = 0.f, e2 = 0.f;
    #pragma unroll
    for (int yy = 0; yy < 11; yy++) {
      e1 += v[3 * (2 * yy)];
      o  += v[3 * (2 * yy + 1)];
      e2 += v[3 * (2 * yy + 2)];
    }
    sxy[zz * 9 + 0 + kx] = e1;
    sxy[zz * 9 + 3 + kx] = o;
    sxy[zz * 9 + 6 + kx] = e2;
  }
  __syncthreads();
  // pass C: 9 tasks (ky,kx) -> 3 z-sums
  if (t < 9) {
    const float* v = sxy + t;
    float e1 = 0.f, o = 0.f, e2 = 0.f;
    #pragma unroll
    for (int zz = 0; zz < 11; zz++) {
      e1 += v[9 * (2 * zz)];
      o  += v[9 * (2 * zz + 1)];
      e2 += v[9 * (2 * zz + 2)];
    }
    ws[WS_WINS + blk * 27 + 0  + t] = e1;
    ws[WS_WINS + blk * 27 + 9  + t] = o;
    ws[WS_WINS + blk * 27 + 18 + t] = e2;
  }
}

// ---------------------------------------------------------------------------
// K_B: xfeat + ctrl chain (flag-synced, producers resident by construction)
//      overlapped with the pred register-preload; combine after final flag.
// ---------------------------------------------------------------------------
__global__ __launch_bounds__(256, 2) void kB_seg(
    const float* __restrict__ pred,
    const float* __restrict__ gap_w, const float* __restrict__ gap_b,
    const float* __restrict__ w_cf,  const float* __restrict__ b_cf,
    const float* __restrict__ w_c,   const float* __restrict__ b_c,
    const float* __restrict__ w_a1,  const float* __restrict__ b_a1,
    const float* __restrict__ w_a2,  const float* __restrict__ b_a2,
    const float* __restrict__ emb,   const float* __restrict__ w_seg,
    const float* __restrict__ b_seg,
    float* ws, float* __restrict__ out) {
  __shared__ float smem[3456];
  __shared__ float ew[192];
  int* sync = (int*)(ws + WS_SYNC);
  int* f0 = sync + 32;   // xfeat done (128)
  int* f1 = sync + 33;   // ctrl1 done (24)
  int* f2 = sync + 34;   // ctrl2 done (12)
  int* f3 = sync + 35;   // effw ready (1)
  const int blk = blockIdx.x;
  const int t = threadIdx.x;

  // ---- stage 1: xfeat on blocks 0..127 ------------------------------------
  if (blk < 128) {
    int b = blk >> 6, oc = blk & 63;       // 64 chunks of 4 outputs
    const float* wp = ws + WS_WINS + b * 3456;
    for (int i = t; i < 3456; i += 256) smem[i] = wp[i];
    __syncthreads();
    int o = oc * 4 + (t >> 6), lane = t & 63;
    const float4* w4 = (const float4*)(gap_w + (size_t)o * 3456);
    const float4* s4 = (const float4*)smem;
    float acc = 0.f;
    for (int i = lane; i < 864; i += 64) {
      float4 wv = w4[i], sv = s4[i];
      acc += wv.x * sv.x + wv.y * sv.y + wv.z * sv.z + wv.w * sv.w;
    }
    #pragma unroll
    for (int off = 32; off; off >>= 1) acc += __shfl_down(acc, off);
    if (lane == 0) ws[WS_XF + b * 256 + o] = acc * (1.f / 1331.f) + gap_b[o];
    __syncthreads();
    if (t == 0) arrive(f0);
  }

  // ---- stage 2: ctrl1 on blocks 0..23 --------------------------------------
  if (blk < 24) {
    wait_cnt(f0, 128);
    int bk = blk >> 2, q = blk & 3;
    int b = bk / 3, k = bk % 3;
    float* cond = smem;
    float* ph   = smem + 512;
    for (int i = t; i < 512; i += 256)
      cond[i] = (i < 256) ? ws[WS_XF + b * 256 + i] : emb[k * 256 + (i - 256)];
    __syncthreads();
    int ol = t & 127, half = t >> 7;
    int o = q * 128 + ol;
    const float4* w4 = (const float4*)(w_cf + (size_t)o * 512) + half * 64;
    const float4* c4 = (const float4*)cond + half * 64;
    float acc = 0.f;
    #pragma unroll 8
    for (int j = 0; j < 64; j++) {
      float4 wv = w4[j], cv = c4[j];
      acc += wv.x * cv.x + wv.y * cv.y + wv.z * cv.z + wv.w * cv.w;
    }
    ph[half * 128 + ol] = acc;
    __syncthreads();
    if (t < 128)
      ws[WS_P + bk * 512 + o] = fmaxf(ph[t] + ph[128 + t] + b_cf[o], 0.f);
    __syncthreads();
    if (t == 0) arrive(f1);
  }

  // ---- stage 3: ctrl2 on blocks 0..11 --------------------------------------
  if (blk < 12) {
    wait_cnt(f1, 24);
    int bk = blk >> 1, h = blk & 1;
    float* pbuf = smem;
    float* ph   = smem + 512;
    for (int i = t; i < 512; i += 256) pbuf[i] = ws[WS_P + bk * 512 + i];
    __syncthreads();
    int ol = t & 127, half = t >> 7;
    int o = h * 128 + ol;
    const float4* w4 = (const float4*)(w_c + (size_t)o * 512) + half * 64;
    const float4* p4 = (const float4*)pbuf + half * 64;
    float acc = 0.f;
    #pragma unroll 8
    for (int j = 0; j < 64; j++) {
      float4 wv = w4[j], pv = p4[j];
      acc += wv.x * pv.x + wv.y * pv.y + wv.z * pv.z + wv.w * pv.w;
    }
    ph[half * 128 + ol] = acc;
    __syncthreads();
    if (t < 128)
      ws[WS_C + bk * 256 + o] = ph[t] + ph[128 + t] + b_c[o];
    __syncthreads();
    if (t == 0) arrive(f2);
  }

  // ---- stage 4: ctrl3 + effw on block 0 ------------------------------------
  if (blk == 0) {
    wait_cnt(f2, 12);
    float* cl  = smem;                 // 1536
    float* hid = smem + 1536;          // 96
    for (int i = t; i < 1536; i += 256) cl[i] = ws[WS_C + i];
    __syncthreads();
    if (t < 96) {
      int bk = t >> 4, h = t & 15;
      const float4* w4 = (const float4*)(w_a1 + h * 256);
      const float4* c4 = (const float4*)(cl + bk * 256);
      float acc = b_a1[h];
      #pragma unroll 8
      for (int j = 0; j < 64; j++) {
        float4 wv = w4[j], cv = c4[j];
        acc += wv.x*cv.x + wv.y*cv.y + wv.z*cv.z + wv.w*cv.w;
      }
      hid[bk * 16 + h] = fmaxf(acc, 0.f);
    }
    __syncthreads();
    if (t < 192) {
      int bk = t >> 5, o = t & 31;
      int k = bk - (bk >= 3) * 3;
      float acc = b_a2[o];
      #pragma unroll
      for (int j = 0; j < 16; j++) acc += w_a2[o * 16 + j] * hid[bk * 16 + j];
      float gate = 1.f / (1.f + __expf(-acc));
      ws[WS_EFFW + bk * 32 + o] = gate * w_seg[k * 32 + o];
    }
    __syncthreads();
    if (t == 0) { __threadfence(); arrive(f3); }
  }

  // ---- stage 5: all blocks — preload pred, wait effw, combine, store ------
  int gid = blk * 256 + t;               // < 442368 exactly
  int b = gid / P4;
  int pp = gid - b * P4;
  const float4* pr = (const float4*)pred + (size_t)b * 32 * P4 + pp;
  float4 v[32];
  #pragma unroll
  for (int c = 0; c < 32; c++) v[c] = pr[(size_t)c * P4];

  wait_cnt(f3, 1);
  if (t < 192) ew[t] = ws[WS_EFFW + t];
  __syncthreads();

  const float* e = ew + b * 96;
  v4f a0 = {0, 0, 0, 0}, a1 = a0, a2 = a0;
  #pragma unroll
  for (int c = 0; c < 32; c++) {
    float w0 = e[c], w1 = e[32 + c], w2 = e[64 + c];
    a0.x += w0 * v[c].x; a0.y += w0 * v[c].y; a0.z += w0 * v[c].z; a0.w += w0 * v[c].w;
    a1.x += w1 * v[c].x; a1.y += w1 * v[c].y; a1.z += w1 * v[c].z; a1.w += w1 * v[c].w;
    a2.x += w2 * v[c].x; a2.y += w2 * v[c].y; a2.z += w2 * v[c].z; a2.w += w2 * v[c].w;
  }
  a0 += b_seg[0];
  a1 += b_seg[1];
  a2 += b_seg[2];
  v4f* o4 = (v4f*)out + (size_t)b * 3 * P4 + pp;
  __builtin_nontemporal_store(a0, o4);
  __builtin_nontemporal_store(a1, o4 + P4);
  __builtin_nontemporal_store(a2, o4 + 2 * P4);
}

extern "C" void kernel_launch(void* const* d_in, const int* in_sizes, int n_in,
                              void* d_out, int out_size, void* d_ws, size_t ws_size,
                              hipStream_t stream) {
  const float* x_e   = (const float*)d_in[0];
  const float* pred  = (const float*)d_in[1];
  const float* gn_g  = (const float*)d_in[2];
  const float* gn_b  = (const float*)d_in[3];
  const float* gap_w = (const float*)d_in[4];
  const float* gap_b = (const float*)d_in[5];
  const float* w_cf  = (const float*)d_in[6];
  const float* b_cf  = (const float*)d_in[7];
  const float* w_c   = (const float*)d_in[8];
  const float* b_c   = (const float*)d_in[9];
  const float* w_a1  = (const float*)d_in[10];
  const float* b_a1  = (const float*)d_in[11];
  const float* w_a2  = (const float*)d_in[12];
  const float* b_a2  = (const float*)d_in[13];
  const float* emb   = (const float*)d_in[14];
  const float* w_seg = (const float*)d_in[15];
  const float* b_seg = (const float*)d_in[16];
  float* ws  = (float*)d_ws;
  float* out = (float*)d_out;

  // zero all sync counters/flags each call/replay (graph-capturable)
  (void)hipMemsetAsync((char*)d_ws + WS_SYNC * 4, 0, 36 * 4, stream);
  kA_winsum<<<256, 256, 0, stream>>>(x_e, gn_g, gn_b, gap_w, w_cf, w_c,
                                     w_a1, emb, ws);
  kB_seg<<<1728, 256, 0, stream>>>(pred, gap_w, gap_b, w_cf, b_cf, w_c, b_c,
                                   w_a1, b_a1, w_a2, b_a2, emb, w_seg, b_seg,
                                   ws, out);
}